// Round 13
// baseline (434.715 us; speedup 1.0000x reference)
//
#include <hip/hip_runtime.h>

typedef __attribute__((ext_vector_type(8))) short bf16x8;
typedef __attribute__((ext_vector_type(4))) float f32x4;

#define MFMA(a,b,c) __builtin_amdgcn_mfma_f32_16x16x32_bf16(a,b,c,0,0,0)

static __device__ __forceinline__ unsigned short f2bf(float f){
  unsigned u = __float_as_uint(f);
  u += 0x7FFF + ((u>>16)&1);
  return (unsigned short)(u>>16);
}
static __device__ __forceinline__ float bf2f(unsigned short b){
  return __uint_as_float(((unsigned)b)<<16);
}

// ---------------- kernel 0: weight swizzle into MFMA fragment order, bf16 hi/lo ----
__global__ __launch_bounds__(256) void wswz(
    const float* __restrict__ wk1, const float* __restrict__ wk2, const float* __restrict__ wk3,
    const float* __restrict__ wq1, const float* __restrict__ wq2, const float* __restrict__ wq3,
    unsigned short* __restrict__ wb)
{
  int y = blockIdx.y;            // net*3 + layer
  int net = y / 3, layer = y % 3;
  const float* src = net ? (layer==0?wq1: layer==1?wq2:wq3)
                         : (layer==0?wk1: layer==1?wk2:wk3);
  int N  = (layer==2) ? 32 : 128;
  int NT = N / 16;
  int total = 32 * NT * 4 * 64;
  int e = blockIdx.x * 256 + threadIdx.x;
  if (e >= total) return;
  int lane = e & 63;
  int ks   = (e >> 6) & 3;
  int nt   = (e >> 8) % NT;
  int h    = (e >> 8) / NT;
  int k0 = ks*32 + 8*(lane>>4);
  int n0 = nt*16 + (lane&15);
  const float* s = src + (size_t)h*128*N + (size_t)k0*N + n0;
  unsigned short hi[8], lo[8];
  #pragma unroll
  for (int j=0;j<8;++j){
    float v = s[(size_t)j*N];
    unsigned short hh = f2bf(v);
    hi[j] = hh;
    lo[j] = f2bf(v - bf2f(hh));
  }
  size_t nb   = (size_t)net * 2359296;
  size_t loff = (layer==0) ? 0 : (layer==1) ? 1048576 : 2097152;
  size_t losz = (layer==2) ? 131072 : 524288;
  size_t eidx = ((((size_t)h*NT + nt)*4 + ks)*64 + lane)*8;
  unsigned short* dH = wb + nb + loff + eidx;
  unsigned short* dL = dH + losz;
  *(bf16x8*)dH = *(const bf16x8*)hi;
  *(bf16x8*)dL = *(const bf16x8*)lo;
}

// ---------------- kernel Z: upper-triangle zero fill, fill-kernel-shaped ----------------
// R13 change (isolated): the 480MB of causal zeros (full tiles tc>tr) move out of
// scores_k into this dedicated kernel. Block = 16 consecutive rows of one bh; all
// 4 waves sweep ONE row at a time -> each wave-instruction writes 1KB CONTIGUOUS
// (vs 16 scattered 64B segments in the old tile path); consecutive blocks ->
// adjacent rows. This is the same address pattern as the 6.5TB/s fill kernels.
__global__ __launch_bounds__(256) void zfill(float* __restrict__ out)
{
  int bid = blockIdx.x;
  int rg = bid & 127;            // 16-row group within bh
  int bh = bid >> 7;
  int tr = rg >> 3;              // tile-row of these 16 rows
  int c0 = (tr + 1) * 128;       // first fully-masked column
  int len = 2048 - c0;           // floats to zero per row (multiple of 128)
  if (len <= 0) return;          // tr==15: nothing
  float* base = out + (size_t)bh*2048*2048 + (size_t)(rg*16)*2048;
  f32x4 z = {0.f,0.f,0.f,0.f};
  int tid = threadIdx.x;
  #pragma unroll 1
  for (int r = 0; r < 16; ++r){
    float* rowp = base + (size_t)r*2048 + c0;
    for (int off = tid*4; off < len; off += 1024)
      *(f32x4*)&rowp[off] = z;
  }
}

// ---------------- kernel 1 (R10 EXACT): per-head 3-layer MLP, swapped-operand MFMA ----
__global__ __launch_bounds__(256,3) void lift(
    const float* __restrict__ Kin, const float* __restrict__ Qin,
    const float* __restrict__ bk1, const float* __restrict__ bk2, const float* __restrict__ bk3,
    const float* __restrict__ bq1, const float* __restrict__ bq2, const float* __restrict__ bq3,
    const unsigned short* __restrict__ wb,
    unsigned short* __restrict__ qlift, unsigned short* __restrict__ klift,
    float* __restrict__ kout)
{
  __shared__ unsigned short XH[64][136];
  __shared__ unsigned short XL[64][136];
  int bid = blockIdx.x;
  int h   = (bid & 7)*4 + ((bid>>3)&3);   // XCD-packed head index
  int st  = (bid>>5) & 31;
  int bb  = (bid>>10) & 1;
  int net = bid>>11;
  size_t rowbase = (size_t)(bb*32 + h)*2048 + (size_t)st*64;
  const float* X = (net ? Qin : Kin) + rowbase*128;
  const unsigned short* wn = wb + (size_t)net*2359296;
  const float* b1 = (net ? bq1 : bk1) + h*128;
  const float* b2 = (net ? bq2 : bk2) + h*128;
  const float* b3 = (net ? bq3 : bk3) + h*32;
  unsigned short* lifto = net ? qlift : klift;

  int tid = threadIdx.x, w = tid >> 6, l = tid & 63;
  int lr = l & 15, lg = l >> 4;
  int acol0 = 8*lg;

  // stage 64 rows x 128 cols as trunc-split hi/lo into LDS (block-wide)
  #pragma unroll
  for (int i=0;i<8;++i){
    int row = i*8 + (tid>>5);
    int col = (tid&31)*4;
    float4 v = *(const float4*)&X[(size_t)row*128 + col];
    unsigned u0=__float_as_uint(v.x), u1=__float_as_uint(v.y),
             u2=__float_as_uint(v.z), u3=__float_as_uint(v.w);
    float l0 = v.x - __uint_as_float(u0 & 0xFFFF0000u);
    float l1 = v.y - __uint_as_float(u1 & 0xFFFF0000u);
    float l2 = v.z - __uint_as_float(u2 & 0xFFFF0000u);
    float l3 = v.w - __uint_as_float(u3 & 0xFFFF0000u);
    *(uint2*)&XH[row][col] = make_uint2((u0>>16) | (u1 & 0xFFFF0000u),
                                        (u2>>16) | (u3 & 0xFFFF0000u));
    *(uint2*)&XL[row][col] = make_uint2((__float_as_uint(l0)>>16) | (__float_as_uint(l1) & 0xFFFF0000u),
                                        (__float_as_uint(l2)>>16) | (__float_as_uint(l3) & 0xFFFF0000u));
  }
  __syncthreads();

  // ================= layers 1 & 2 (K=128 -> N=128, silu) =================
  for (int L=0; L<2; ++L){
    const unsigned short* wH = wn + (size_t)L*1048576;
    const unsigned short* wL = wH + 524288;
    const float* bias = L ? b2 : b1;
    f32x4 acc[2][4];
    #pragma unroll
    for (int ntl=0;ntl<2;++ntl)
      #pragma unroll
      for (int rt=0;rt<4;++rt)
        acc[ntl][rt] = (f32x4){0.f,0.f,0.f,0.f};

    #pragma unroll
    for (int ks=0;ks<4;++ks){
      bf16x8 bh[2], bl[2];
      #pragma unroll
      for (int ntl=0;ntl<2;++ntl){
        size_t eidx = ((((size_t)h*8 + (w*2+ntl))*4 + ks)*64 + l)*8;
        bh[ntl] = *(const bf16x8*)(wH + eidx);
        bl[ntl] = *(const bf16x8*)(wL + eidx);
      }
      #pragma unroll
      for (int rt=0;rt<4;++rt){
        bf16x8 ah = *(const bf16x8*)&XH[rt*16+lr][ks*32 + acol0];
        bf16x8 al = *(const bf16x8*)&XL[rt*16+lr][ks*32 + acol0];
        #pragma unroll
        for (int ntl=0;ntl<2;++ntl){
          f32x4 a = acc[ntl][rt];
          a = MFMA(bh[ntl], ah, a);   // Wh * Xh
          a = MFMA(bh[ntl], al, a);   // Wh * Xl
          a = MFMA(bl[ntl], ah, a);   // Wl * Xh
          acc[ntl][rt] = a;
        }
      }
    }
    __syncthreads();   // all reads of previous acts complete before overwrite
    #pragma unroll
    for (int ntl=0;ntl<2;++ntl){
      int n0 = (w*2+ntl)*16 + 4*lg;   // 4 consecutive output features
      float4 bv = *(const float4*)&bias[n0];
      float bvv[4] = {bv.x, bv.y, bv.z, bv.w};
      #pragma unroll
      for (int rt=0;rt<4;++rt){
        int row = rt*16 + lr;          // act row owned by this lane
        unsigned hh[4], ll[4];
        #pragma unroll
        for (int i=0;i<4;++i){
          float v = acc[ntl][rt][i] + bvv[i];
          float sg = v * __builtin_amdgcn_rcpf(1.f + __expf(-v));
          unsigned u = __float_as_uint(sg);
          hh[i] = u >> 16;
          float lo = sg - __uint_as_float(u & 0xFFFF0000u);
          ll[i] = __float_as_uint(lo) >> 16;
        }
        *(uint2*)&XH[row][n0] = make_uint2(hh[0] | (hh[1]<<16), hh[2] | (hh[3]<<16));
        *(uint2*)&XL[row][n0] = make_uint2(ll[0] | (ll[1]<<16), ll[2] | (ll[3]<<16));
      }
    }
    __syncthreads();
  }

  // ================= layer 3 (K=128 -> N=32, tanh) + packed stores =================
  {
    const unsigned short* wH = wn + 2097152;
    const unsigned short* wL = wH + 131072;
    int nt = w >> 1;
    int rb = (w & 1) * 2;
    f32x4 acc3[2];
    acc3[0] = (f32x4){0.f,0.f,0.f,0.f};
    acc3[1] = (f32x4){0.f,0.f,0.f,0.f};
    #pragma unroll
    for (int ks=0;ks<4;++ks){
      size_t eidx = ((((size_t)h*2 + nt)*4 + ks)*64 + l)*8;
      bf16x8 bh = *(const bf16x8*)(wH + eidx);
      bf16x8 bl = *(const bf16x8*)(wL + eidx);
      #pragma unroll
      for (int j=0;j<2;++j){
        bf16x8 ah = *(const bf16x8*)&XH[(rb+j)*16+lr][ks*32 + acol0];
        bf16x8 al = *(const bf16x8*)&XL[(rb+j)*16+lr][ks*32 + acol0];
        f32x4 a = acc3[j];
        a = MFMA(bh, ah, a);
        a = MFMA(bh, al, a);
        a = MFMA(bl, ah, a);
        acc3[j] = a;
      }
    }
    int n0 = nt*16 + 4*lg;
    float4 bv = *(const float4*)&b3[n0];
    float bvv[4] = {bv.x, bv.y, bv.z, bv.w};
    #pragma unroll
    for (int j=0;j<2;++j){
      int row = (rb+j)*16 + lr;
      float t4[4];
      unsigned short hb[4];
      #pragma unroll
      for (int i=0;i<4;++i){
        float v = acc3[j][i] + bvv[i];
        float e2 = __expf(2.f*v);
        float t  = 1.f - 2.f*__builtin_amdgcn_rcpf(e2 + 1.f);
        t4[i] = t;
        hb[i] = f2bf(t);               // RNE for final bf16 (feeds scores)
      }
      size_t gro = (rowbase + (size_t)row)*32 + n0;
      *(uint2*)&lifto[gro] = make_uint2((unsigned)hb[0] | ((unsigned)hb[1]<<16),
                                        (unsigned)hb[2] | ((unsigned)hb[3]<<16));
      if (net == 0)
        *(float4*)&kout[gro] = make_float4(t4[0], t4[1], t4[2], t4[3]);
    }
  }
}

// ---------------- kernel 2: scores = sigmoid(masked(Qlift @ Klift^T)), lower+diag only --
// Compute path EXACT R4/R8/R10. Upper tiles handled by zfill -> early return.
__global__ __launch_bounds__(256) void scores_k(
    const unsigned short* __restrict__ qlift,
    const unsigned short* __restrict__ klift,
    float* __restrict__ out)
{
  int bid = blockIdx.x;
  int tc = bid & 15, tr = (bid >> 4) & 15, bh = bid >> 8;
  if (tc > tr) return;   // zero-filled by zfill
  size_t sbase = (size_t)bh * 2048 * 2048;
  int r0 = tr * 128, c0 = tc * 128;   // r0: t rows (Q), c0: s cols (K)
  int tid = threadIdx.x;

  int w = tid >> 6, l = tid & 63;
  int lr = l & 15, lg = l >> 4;
  int acol0 = 8*lg;
  // B operand: Q fragments for t-tiles {w*32, w*32+16}
  const unsigned short* qb = qlift + ((size_t)bh*2048 + r0 + w*32)*32;
  bf16x8 q0 = *(const bf16x8*)(qb + (size_t)lr*32 + acol0);
  bf16x8 q1 = *(const bf16x8*)(qb + (size_t)(16+lr)*32 + acol0);
  bool diag = (tc == tr);
  int t0 = r0 + w*32 + lr;
  int t1 = t0 + 16;

  // A operand: K fragments for the 8 s-tiles (prefetch all)
  const unsigned short* kb = klift + ((size_t)bh*2048 + c0)*32;
  bf16x8 kf[8];
  #pragma unroll
  for (int st8=0; st8<8; ++st8)
    kf[st8] = *(const bf16x8*)(kb + (size_t)(st8*16+lr)*32 + acol0);

  #pragma unroll
  for (int st8=0; st8<8; ++st8){
    f32x4 z4 = {0.f,0.f,0.f,0.f};
    f32x4 s0 = MFMA(kf[st8], q0, z4);   // D[s][t0-range]
    f32x4 s1 = MFMA(kf[st8], q1, z4);   // D[s][t1-range]
    int scol = c0 + st8*16 + 4*lg;
    f32x4 p0, p1;
    #pragma unroll
    for (int i=0;i<4;++i){
      float v0 = s0[i];
      float pv0 = __builtin_amdgcn_rcpf(1.f + __expf(-v0));
      if (diag && (scol + i > t0)) pv0 = 0.f;
      p0[i] = pv0;
      float v1 = s1[i];
      float pv1 = __builtin_amdgcn_rcpf(1.f + __expf(-v1));
      if (diag && (scol + i > t1)) pv1 = 0.f;
      p1[i] = pv1;
    }
    *(f32x4*)&out[sbase + (size_t)t0*2048 + scol] = p0;
    *(f32x4*)&out[sbase + (size_t)t1*2048 + scol] = p1;
  }
}

extern "C" void kernel_launch(void* const* d_in, const int* in_sizes, int n_in,
                              void* d_out, int out_size, void* d_ws, size_t ws_size,
                              hipStream_t stream) {
  const float* K   = (const float*)d_in[0];
  const float* Q   = (const float*)d_in[1];
  const float* wk1 = (const float*)d_in[2];  const float* bk1 = (const float*)d_in[3];
  const float* wk2 = (const float*)d_in[4];  const float* bk2 = (const float*)d_in[5];
  const float* wk3 = (const float*)d_in[6];  const float* bk3 = (const float*)d_in[7];
  const float* wq1 = (const float*)d_in[8];  const float* bq1 = (const float*)d_in[9];
  const float* wq2 = (const float*)d_in[10]; const float* bq2 = (const float*)d_in[11];
  const float* wq3 = (const float*)d_in[12]; const float* bq3 = (const float*)d_in[13];
  float* out = (float*)d_out;

  unsigned short* ws    = (unsigned short*)d_ws;
  unsigned short* qlift = ws;                 // 4,194,304 ushorts
  unsigned short* klift = ws + 4194304;       // 4,194,304 ushorts
  unsigned short* wbase = ws + 8388608;       // 2 nets * 2,359,296 ushorts

  hipLaunchKernelGGL(wswz, dim3(256,6), dim3(256), 0, stream,
                     wk1, wk2, wk3, wq1, wq2, wq3, wbase);
  hipLaunchKernelGGL(zfill, dim3(8192), dim3(256), 0, stream, out);
  hipLaunchKernelGGL(lift, dim3(4096), dim3(256), 0, stream,
                     K, Q, bk1, bk2, bk3, bq1, bq2, bq3,
                     wbase, qlift, klift, out + 268435456ull);
  hipLaunchKernelGGL(scores_k, dim3(16384), dim3(256), 0, stream,
                     qlift, klift, out);
}

// Round 14
// 286.816 us; speedup vs baseline: 1.5157x; 1.5157x over previous
//
#include <hip/hip_runtime.h>

typedef __attribute__((ext_vector_type(8))) short bf16x8;
typedef __attribute__((ext_vector_type(4))) float f32x4;

#define MFMA(a,b,c) __builtin_amdgcn_mfma_f32_16x16x32_bf16(a,b,c,0,0,0)

static __device__ __forceinline__ unsigned short f2bf(float f){
  unsigned u = __float_as_uint(f);
  u += 0x7FFF + ((u>>16)&1);
  return (unsigned short)(u>>16);
}
static __device__ __forceinline__ float bf2f(unsigned short b){
  return __uint_as_float(((unsigned)b)<<16);
}

// ---------------- kernel 0: weight swizzle into MFMA fragment order, bf16 hi/lo ----
__global__ __launch_bounds__(256) void wswz(
    const float* __restrict__ wk1, const float* __restrict__ wk2, const float* __restrict__ wk3,
    const float* __restrict__ wq1, const float* __restrict__ wq2, const float* __restrict__ wq3,
    unsigned short* __restrict__ wb)
{
  int y = blockIdx.y;            // net*3 + layer
  int net = y / 3, layer = y % 3;
  const float* src = net ? (layer==0?wq1: layer==1?wq2:wq3)
                         : (layer==0?wk1: layer==1?wk2:wk3);
  int N  = (layer==2) ? 32 : 128;
  int NT = N / 16;
  int total = 32 * NT * 4 * 64;
  int e = blockIdx.x * 256 + threadIdx.x;
  if (e >= total) return;
  int lane = e & 63;
  int ks   = (e >> 6) & 3;
  int nt   = (e >> 8) % NT;
  int h    = (e >> 8) / NT;
  int k0 = ks*32 + 8*(lane>>4);
  int n0 = nt*16 + (lane&15);
  const float* s = src + (size_t)h*128*N + (size_t)k0*N + n0;
  unsigned short hi[8], lo[8];
  #pragma unroll
  for (int j=0;j<8;++j){
    float v = s[(size_t)j*N];
    unsigned short hh = f2bf(v);
    hi[j] = hh;
    lo[j] = f2bf(v - bf2f(hh));
  }
  size_t nb   = (size_t)net * 2359296;
  size_t loff = (layer==0) ? 0 : (layer==1) ? 1048576 : 2097152;
  size_t losz = (layer==2) ? 131072 : 524288;
  size_t eidx = ((((size_t)h*NT + nt)*4 + ks)*64 + lane)*8;
  unsigned short* dH = wb + nb + loff + eidx;
  unsigned short* dL = dH + losz;
  *(bf16x8*)dH = *(const bf16x8*)hi;
  *(bf16x8*)dL = *(const bf16x8*)lo;
}

// ---------------- kernel 1 (R10 EXACT, 318us config): per-head 3-layer MLP ----------
__global__ __launch_bounds__(256,3) void lift(
    const float* __restrict__ Kin, const float* __restrict__ Qin,
    const float* __restrict__ bk1, const float* __restrict__ bk2, const float* __restrict__ bk3,
    const float* __restrict__ bq1, const float* __restrict__ bq2, const float* __restrict__ bq3,
    const unsigned short* __restrict__ wb,
    unsigned short* __restrict__ qlift, unsigned short* __restrict__ klift,
    float* __restrict__ kout)
{
  __shared__ unsigned short XH[64][136];
  __shared__ unsigned short XL[64][136];
  int bid = blockIdx.x;
  int h   = (bid & 7)*4 + ((bid>>3)&3);   // XCD-packed head index
  int st  = (bid>>5) & 31;
  int bb  = (bid>>10) & 1;
  int net = bid>>11;
  size_t rowbase = (size_t)(bb*32 + h)*2048 + (size_t)st*64;
  const float* X = (net ? Qin : Kin) + rowbase*128;
  const unsigned short* wn = wb + (size_t)net*2359296;
  const float* b1 = (net ? bq1 : bk1) + h*128;
  const float* b2 = (net ? bq2 : bk2) + h*128;
  const float* b3 = (net ? bq3 : bk3) + h*32;
  unsigned short* lifto = net ? qlift : klift;

  int tid = threadIdx.x, w = tid >> 6, l = tid & 63;
  int lr = l & 15, lg = l >> 4;
  int acol0 = 8*lg;

  // stage 64 rows x 128 cols as trunc-split hi/lo into LDS (block-wide)
  #pragma unroll
  for (int i=0;i<8;++i){
    int row = i*8 + (tid>>5);
    int col = (tid&31)*4;
    float4 v = *(const float4*)&X[(size_t)row*128 + col];
    unsigned u0=__float_as_uint(v.x), u1=__float_as_uint(v.y),
             u2=__float_as_uint(v.z), u3=__float_as_uint(v.w);
    float l0 = v.x - __uint_as_float(u0 & 0xFFFF0000u);
    float l1 = v.y - __uint_as_float(u1 & 0xFFFF0000u);
    float l2 = v.z - __uint_as_float(u2 & 0xFFFF0000u);
    float l3 = v.w - __uint_as_float(u3 & 0xFFFF0000u);
    *(uint2*)&XH[row][col] = make_uint2((u0>>16) | (u1 & 0xFFFF0000u),
                                        (u2>>16) | (u3 & 0xFFFF0000u));
    *(uint2*)&XL[row][col] = make_uint2((__float_as_uint(l0)>>16) | (__float_as_uint(l1) & 0xFFFF0000u),
                                        (__float_as_uint(l2)>>16) | (__float_as_uint(l3) & 0xFFFF0000u));
  }
  __syncthreads();

  // ================= layers 1 & 2 (K=128 -> N=128, silu) =================
  for (int L=0; L<2; ++L){
    const unsigned short* wH = wn + (size_t)L*1048576;
    const unsigned short* wL = wH + 524288;
    const float* bias = L ? b2 : b1;
    f32x4 acc[2][4];
    #pragma unroll
    for (int ntl=0;ntl<2;++ntl)
      #pragma unroll
      for (int rt=0;rt<4;++rt)
        acc[ntl][rt] = (f32x4){0.f,0.f,0.f,0.f};

    #pragma unroll
    for (int ks=0;ks<4;++ks){
      bf16x8 bh[2], bl[2];
      #pragma unroll
      for (int ntl=0;ntl<2;++ntl){
        size_t eidx = ((((size_t)h*8 + (w*2+ntl))*4 + ks)*64 + l)*8;
        bh[ntl] = *(const bf16x8*)(wH + eidx);
        bl[ntl] = *(const bf16x8*)(wL + eidx);
      }
      #pragma unroll
      for (int rt=0;rt<4;++rt){
        bf16x8 ah = *(const bf16x8*)&XH[rt*16+lr][ks*32 + acol0];
        bf16x8 al = *(const bf16x8*)&XL[rt*16+lr][ks*32 + acol0];
        #pragma unroll
        for (int ntl=0;ntl<2;++ntl){
          f32x4 a = acc[ntl][rt];
          a = MFMA(bh[ntl], ah, a);   // Wh * Xh
          a = MFMA(bh[ntl], al, a);   // Wh * Xl
          a = MFMA(bl[ntl], ah, a);   // Wl * Xh
          acc[ntl][rt] = a;
        }
      }
    }
    __syncthreads();   // all reads of previous acts complete before overwrite
    #pragma unroll
    for (int ntl=0;ntl<2;++ntl){
      int n0 = (w*2+ntl)*16 + 4*lg;   // 4 consecutive output features
      float4 bv = *(const float4*)&bias[n0];
      float bvv[4] = {bv.x, bv.y, bv.z, bv.w};
      #pragma unroll
      for (int rt=0;rt<4;++rt){
        int row = rt*16 + lr;          // act row owned by this lane
        unsigned hh[4], ll[4];
        #pragma unroll
        for (int i=0;i<4;++i){
          float v = acc[ntl][rt][i] + bvv[i];
          float sg = v * __builtin_amdgcn_rcpf(1.f + __expf(-v));
          unsigned u = __float_as_uint(sg);
          hh[i] = u >> 16;
          float lo = sg - __uint_as_float(u & 0xFFFF0000u);
          ll[i] = __float_as_uint(lo) >> 16;
        }
        *(uint2*)&XH[row][n0] = make_uint2(hh[0] | (hh[1]<<16), hh[2] | (hh[3]<<16));
        *(uint2*)&XL[row][n0] = make_uint2(ll[0] | (ll[1]<<16), ll[2] | (ll[3]<<16));
      }
    }
    __syncthreads();
  }

  // ================= layer 3 (K=128 -> N=32, tanh) + packed stores =================
  {
    const unsigned short* wH = wn + 2097152;
    const unsigned short* wL = wH + 131072;
    int nt = w >> 1;
    int rb = (w & 1) * 2;
    f32x4 acc3[2];
    acc3[0] = (f32x4){0.f,0.f,0.f,0.f};
    acc3[1] = (f32x4){0.f,0.f,0.f,0.f};
    #pragma unroll
    for (int ks=0;ks<4;++ks){
      size_t eidx = ((((size_t)h*2 + nt)*4 + ks)*64 + l)*8;
      bf16x8 bh = *(const bf16x8*)(wH + eidx);
      bf16x8 bl = *(const bf16x8*)(wL + eidx);
      #pragma unroll
      for (int j=0;j<2;++j){
        bf16x8 ah = *(const bf16x8*)&XH[(rb+j)*16+lr][ks*32 + acol0];
        bf16x8 al = *(const bf16x8*)&XL[(rb+j)*16+lr][ks*32 + acol0];
        f32x4 a = acc3[j];
        a = MFMA(bh, ah, a);
        a = MFMA(bh, al, a);
        a = MFMA(bl, ah, a);
        acc3[j] = a;
      }
    }
    int n0 = nt*16 + 4*lg;
    float4 bv = *(const float4*)&b3[n0];
    float bvv[4] = {bv.x, bv.y, bv.z, bv.w};
    #pragma unroll
    for (int j=0;j<2;++j){
      int row = (rb+j)*16 + lr;
      float t4[4];
      unsigned short hb[4];
      #pragma unroll
      for (int i=0;i<4;++i){
        float v = acc3[j][i] + bvv[i];
        float e2 = __expf(2.f*v);
        float t  = 1.f - 2.f*__builtin_amdgcn_rcpf(e2 + 1.f);
        t4[i] = t;
        hb[i] = f2bf(t);               // RNE for final bf16 (feeds scores)
      }
      size_t gro = (rowbase + (size_t)row)*32 + n0;
      *(uint2*)&lifto[gro] = make_uint2((unsigned)hb[0] | ((unsigned)hb[1]<<16),
                                        (unsigned)hb[2] | ((unsigned)hb[3]<<16));
      if (net == 0)
        *(float4*)&kout[gro] = make_float4(t4[0], t4[1], t4[2], t4[3]);
    }
  }
}

// ---------------- kernel 2 v3: scores with per-wave LDS-transposed CONTIGUOUS stores ----
// R14 change (isolated): compute tiles route D through a wave-private 16x128 f32
// LDS buffer (XOR-swizzled, NO barriers needed) so each global store instruction
// writes two 512B contiguous row-bursts (one burst per output row) instead of 16
// scattered 64B lines across 16 rows. Theory: the scattered pattern's ~10^4
// concurrent DRAM row-streams page-thrash (zero-tile paths, which are contiguous,
// measured ~free in R10/R13). Tile structure, kf[8] K-reuse, MFMA count, sigmoid,
// predication, and the zero-tile path are byte-identical to R10.
__global__ __launch_bounds__(256) void scores_k(
    const unsigned short* __restrict__ qlift,
    const unsigned short* __restrict__ klift,
    float* __restrict__ out)
{
  int bid = blockIdx.x;
  int tc = bid & 15, tr = (bid >> 4) & 15, bh = bid >> 8;
  size_t sbase = (size_t)bh * 2048 * 2048;
  int r0 = tr * 128, c0 = tc * 128;   // r0: t rows (Q), c0: s cols (K)
  int tid = threadIdx.x;

  if (tc > tr){ // fully masked tile: sigmoid(f32_min) == 0 (exact R10 path)
    float4 z = {0.f,0.f,0.f,0.f};
    #pragma unroll
    for (int it=0; it<16; ++it){
      int idx = it*256 + tid;     // 0..4095
      int row = idx >> 5, c4 = idx & 31;
      *(float4*)&out[sbase + (size_t)(r0+row)*2048 + c0 + c4*4] = z;
    }
    return;
  }

  __shared__ float sbuf[4][16][128];   // per-wave 8KB transpose buffer
  int w = tid >> 6, l = tid & 63;
  int lr = l & 15, lg = l >> 4;
  int acol0 = 8*lg;
  float* sw = &sbuf[w][0][0];

  // B operand: Q fragments for t-tiles {w*32, w*32+16}
  const unsigned short* qb = qlift + ((size_t)bh*2048 + r0 + w*32)*32;
  bf16x8 q0 = *(const bf16x8*)(qb + (size_t)lr*32 + acol0);
  bf16x8 q1 = *(const bf16x8*)(qb + (size_t)(16+lr)*32 + acol0);
  bool diag = (tc == tr);

  // A operand: K fragments for the 8 s-tiles (prefetch all, reused both passes)
  const unsigned short* kb = klift + ((size_t)bh*2048 + c0)*32;
  bf16x8 kf[8];
  #pragma unroll
  for (int st8=0; st8<8; ++st8)
    kf[st8] = *(const bf16x8*)(kb + (size_t)(st8*16+lr)*32 + acol0);

  #pragma unroll
  for (int pass=0; pass<2; ++pass){
    bf16x8 qf = pass ? q1 : q0;
    int tbase = r0 + w*32 + pass*16;   // global t of LDS row 0
    int t = tbase + lr;                // this lane's t (for diag predication)

    #pragma unroll
    for (int st8=0; st8<8; ++st8){
      f32x4 z4 = {0.f,0.f,0.f,0.f};
      f32x4 d = MFMA(kf[st8], qf, z4);   // D[row]=s (4lg+i), D[col]=t (lr)
      int scol = c0 + st8*16 + 4*lg;
      f32x4 p;
      #pragma unroll
      for (int i=0;i<4;++i){
        float pv = __builtin_amdgcn_rcpf(1.f + __expf(-d[i]));
        if (diag && (scol + i > t)) pv = 0.f;
        p[i] = pv;
      }
      int fi = (lr*128 + st8*16 + lg*4) ^ ((lr&7)<<2);   // XOR-swizzled float idx
      *(f32x4*)&sw[fi] = p;
    }
    // readback: 8 instructions, each stores TWO 512B contiguous row-bursts
    #pragma unroll
    for (int it=0; it<8; ++it){
      int r  = it*2 + (l>>5);            // LDS row 0..15
      int fi = (r*128 + (l&31)*4) ^ ((r&7)<<2);
      f32x4 v = *(const f32x4*)&sw[fi];
      *(f32x4*)&out[sbase + (size_t)(tbase + r)*2048 + c0 + (l&31)*4] = v;
    }
  }
}

extern "C" void kernel_launch(void* const* d_in, const int* in_sizes, int n_in,
                              void* d_out, int out_size, void* d_ws, size_t ws_size,
                              hipStream_t stream) {
  const float* K   = (const float*)d_in[0];
  const float* Q   = (const float*)d_in[1];
  const float* wk1 = (const float*)d_in[2];  const float* bk1 = (const float*)d_in[3];
  const float* wk2 = (const float*)d_in[4];  const float* bk2 = (const float*)d_in[5];
  const float* wk3 = (const float*)d_in[6];  const float* bk3 = (const float*)d_in[7];
  const float* wq1 = (const float*)d_in[8];  const float* bq1 = (const float*)d_in[9];
  const float* wq2 = (const float*)d_in[10]; const float* bq2 = (const float*)d_in[11];
  const float* wq3 = (const float*)d_in[12]; const float* bq3 = (const float*)d_in[13];
  float* out = (float*)d_out;

  unsigned short* ws    = (unsigned short*)d_ws;
  unsigned short* qlift = ws;                 // 4,194,304 ushorts
  unsigned short* klift = ws + 4194304;       // 4,194,304 ushorts
  unsigned short* wbase = ws + 8388608;       // 2 nets * 2,359,296 ushorts

  hipLaunchKernelGGL(wswz, dim3(256,6), dim3(256), 0, stream,
                     wk1, wk2, wk3, wq1, wq2, wq3, wbase);
  hipLaunchKernelGGL(lift, dim3(4096), dim3(256), 0, stream,
                     K, Q, bk1, bk2, bk3, bq1, bq2, bq3,
                     wbase, qlift, klift, out + 268435456ull);
  hipLaunchKernelGGL(scores_k, dim3(16384), dim3(256), 0, stream,
                     qlift, klift, out);
}

// Round 15
// 279.910 us; speedup vs baseline: 1.5531x; 1.0247x over previous
//
#include <hip/hip_runtime.h>

typedef __attribute__((ext_vector_type(8))) short bf16x8;
typedef __attribute__((ext_vector_type(4))) float f32x4;

#define MFMA(a,b,c) __builtin_amdgcn_mfma_f32_16x16x32_bf16(a,b,c,0,0,0)

static __device__ __forceinline__ unsigned short f2bf(float f){
  unsigned u = __float_as_uint(f);
  u += 0x7FFF + ((u>>16)&1);
  return (unsigned short)(u>>16);
}
static __device__ __forceinline__ float bf2f(unsigned short b){
  return __uint_as_float(((unsigned)b)<<16);
}

// ---------------- kernel 0: weight swizzle into MFMA fragment order, bf16 hi/lo ----
__global__ __launch_bounds__(256) void wswz(
    const float* __restrict__ wk1, const float* __restrict__ wk2, const float* __restrict__ wk3,
    const float* __restrict__ wq1, const float* __restrict__ wq2, const float* __restrict__ wq3,
    unsigned short* __restrict__ wb)
{
  int y = blockIdx.y;            // net*3 + layer
  int net = y / 3, layer = y % 3;
  const float* src = net ? (layer==0?wq1: layer==1?wq2:wq3)
                         : (layer==0?wk1: layer==1?wk2:wk3);
  int N  = (layer==2) ? 32 : 128;
  int NT = N / 16;
  int total = 32 * NT * 4 * 64;
  int e = blockIdx.x * 256 + threadIdx.x;
  if (e >= total) return;
  int lane = e & 63;
  int ks   = (e >> 6) & 3;
  int nt   = (e >> 8) % NT;
  int h    = (e >> 8) / NT;
  int k0 = ks*32 + 8*(lane>>4);
  int n0 = nt*16 + (lane&15);
  const float* s = src + (size_t)h*128*N + (size_t)k0*N + n0;
  unsigned short hi[8], lo[8];
  #pragma unroll
  for (int j=0;j<8;++j){
    float v = s[(size_t)j*N];
    unsigned short hh = f2bf(v);
    hi[j] = hh;
    lo[j] = f2bf(v - bf2f(hh));
  }
  size_t nb   = (size_t)net * 2359296;
  size_t loff = (layer==0) ? 0 : (layer==1) ? 1048576 : 2097152;
  size_t losz = (layer==2) ? 131072 : 524288;
  size_t eidx = ((((size_t)h*NT + nt)*4 + ks)*64 + lane)*8;
  unsigned short* dH = wb + nb + loff + eidx;
  unsigned short* dL = dH + losz;
  *(bf16x8*)dH = *(const bf16x8*)hi;
  *(bf16x8*)dL = *(const bf16x8*)lo;
}

// ---------------- kernel 1 (R10 EXACT): per-head 3-layer MLP, swapped-operand MFMA ----
__global__ __launch_bounds__(256,3) void lift(
    const float* __restrict__ Kin, const float* __restrict__ Qin,
    const float* __restrict__ bk1, const float* __restrict__ bk2, const float* __restrict__ bk3,
    const float* __restrict__ bq1, const float* __restrict__ bq2, const float* __restrict__ bq3,
    const unsigned short* __restrict__ wb,
    unsigned short* __restrict__ qlift, unsigned short* __restrict__ klift,
    float* __restrict__ kout)
{
  __shared__ unsigned short XH[64][136];
  __shared__ unsigned short XL[64][136];
  int bid = blockIdx.x;
  int h   = (bid & 7)*4 + ((bid>>3)&3);   // XCD-packed head index
  int st  = (bid>>5) & 31;
  int bb  = (bid>>10) & 1;
  int net = bid>>11;
  size_t rowbase = (size_t)(bb*32 + h)*2048 + (size_t)st*64;
  const float* X = (net ? Qin : Kin) + rowbase*128;
  const unsigned short* wn = wb + (size_t)net*2359296;
  const float* b1 = (net ? bq1 : bk1) + h*128;
  const float* b2 = (net ? bq2 : bk2) + h*128;
  const float* b3 = (net ? bq3 : bk3) + h*32;
  unsigned short* lifto = net ? qlift : klift;

  int tid = threadIdx.x, w = tid >> 6, l = tid & 63;
  int lr = l & 15, lg = l >> 4;
  int acol0 = 8*lg;

  // stage 64 rows x 128 cols as trunc-split hi/lo into LDS (block-wide)
  #pragma unroll
  for (int i=0;i<8;++i){
    int row = i*8 + (tid>>5);
    int col = (tid&31)*4;
    float4 v = *(const float4*)&X[(size_t)row*128 + col];
    unsigned u0=__float_as_uint(v.x), u1=__float_as_uint(v.y),
             u2=__float_as_uint(v.z), u3=__float_as_uint(v.w);
    float l0 = v.x - __uint_as_float(u0 & 0xFFFF0000u);
    float l1 = v.y - __uint_as_float(u1 & 0xFFFF0000u);
    float l2 = v.z - __uint_as_float(u2 & 0xFFFF0000u);
    float l3 = v.w - __uint_as_float(u3 & 0xFFFF0000u);
    *(uint2*)&XH[row][col] = make_uint2((u0>>16) | (u1 & 0xFFFF0000u),
                                        (u2>>16) | (u3 & 0xFFFF0000u));
    *(uint2*)&XL[row][col] = make_uint2((__float_as_uint(l0)>>16) | (__float_as_uint(l1) & 0xFFFF0000u),
                                        (__float_as_uint(l2)>>16) | (__float_as_uint(l3) & 0xFFFF0000u));
  }
  __syncthreads();

  // ================= layers 1 & 2 (K=128 -> N=128, silu) =================
  for (int L=0; L<2; ++L){
    const unsigned short* wH = wn + (size_t)L*1048576;
    const unsigned short* wL = wH + 524288;
    const float* bias = L ? b2 : b1;
    f32x4 acc[2][4];
    #pragma unroll
    for (int ntl=0;ntl<2;++ntl)
      #pragma unroll
      for (int rt=0;rt<4;++rt)
        acc[ntl][rt] = (f32x4){0.f,0.f,0.f,0.f};

    #pragma unroll
    for (int ks=0;ks<4;++ks){
      bf16x8 bh[2], bl[2];
      #pragma unroll
      for (int ntl=0;ntl<2;++ntl){
        size_t eidx = ((((size_t)h*8 + (w*2+ntl))*4 + ks)*64 + l)*8;
        bh[ntl] = *(const bf16x8*)(wH + eidx);
        bl[ntl] = *(const bf16x8*)(wL + eidx);
      }
      #pragma unroll
      for (int rt=0;rt<4;++rt){
        bf16x8 ah = *(const bf16x8*)&XH[rt*16+lr][ks*32 + acol0];
        bf16x8 al = *(const bf16x8*)&XL[rt*16+lr][ks*32 + acol0];
        #pragma unroll
        for (int ntl=0;ntl<2;++ntl){
          f32x4 a = acc[ntl][rt];
          a = MFMA(bh[ntl], ah, a);   // Wh * Xh
          a = MFMA(bh[ntl], al, a);   // Wh * Xl
          a = MFMA(bl[ntl], ah, a);   // Wl * Xh
          acc[ntl][rt] = a;
        }
      }
    }
    __syncthreads();   // all reads of previous acts complete before overwrite
    #pragma unroll
    for (int ntl=0;ntl<2;++ntl){
      int n0 = (w*2+ntl)*16 + 4*lg;   // 4 consecutive output features
      float4 bv = *(const float4*)&bias[n0];
      float bvv[4] = {bv.x, bv.y, bv.z, bv.w};
      #pragma unroll
      for (int rt=0;rt<4;++rt){
        int row = rt*16 + lr;          // act row owned by this lane
        unsigned hh[4], ll[4];
        #pragma unroll
        for (int i=0;i<4;++i){
          float v = acc[ntl][rt][i] + bvv[i];
          float sg = v * __builtin_amdgcn_rcpf(1.f + __expf(-v));
          unsigned u = __float_as_uint(sg);
          hh[i] = u >> 16;
          float lo = sg - __uint_as_float(u & 0xFFFF0000u);
          ll[i] = __float_as_uint(lo) >> 16;
        }
        *(uint2*)&XH[row][n0] = make_uint2(hh[0] | (hh[1]<<16), hh[2] | (hh[3]<<16));
        *(uint2*)&XL[row][n0] = make_uint2(ll[0] | (ll[1]<<16), ll[2] | (ll[3]<<16));
      }
    }
    __syncthreads();
  }

  // ================= layer 3 (K=128 -> N=32, tanh) + packed stores =================
  {
    const unsigned short* wH = wn + 2097152;
    const unsigned short* wL = wH + 131072;
    int nt = w >> 1;
    int rb = (w & 1) * 2;
    f32x4 acc3[2];
    acc3[0] = (f32x4){0.f,0.f,0.f,0.f};
    acc3[1] = (f32x4){0.f,0.f,0.f,0.f};
    #pragma unroll
    for (int ks=0;ks<4;++ks){
      size_t eidx = ((((size_t)h*2 + nt)*4 + ks)*64 + l)*8;
      bf16x8 bh = *(const bf16x8*)(wH + eidx);
      bf16x8 bl = *(const bf16x8*)(wL + eidx);
      #pragma unroll
      for (int j=0;j<2;++j){
        bf16x8 ah = *(const bf16x8*)&XH[(rb+j)*16+lr][ks*32 + acol0];
        bf16x8 al = *(const bf16x8*)&XL[(rb+j)*16+lr][ks*32 + acol0];
        f32x4 a = acc3[j];
        a = MFMA(bh, ah, a);
        a = MFMA(bh, al, a);
        a = MFMA(bl, ah, a);
        acc3[j] = a;
      }
    }
    int n0 = nt*16 + 4*lg;
    float4 bv = *(const float4*)&b3[n0];
    float bvv[4] = {bv.x, bv.y, bv.z, bv.w};
    #pragma unroll
    for (int j=0;j<2;++j){
      int row = (rb+j)*16 + lr;
      float t4[4];
      unsigned short hb[4];
      #pragma unroll
      for (int i=0;i<4;++i){
        float v = acc3[j][i] + bvv[i];
        float e2 = __expf(2.f*v);
        float t  = 1.f - 2.f*__builtin_amdgcn_rcpf(e2 + 1.f);
        t4[i] = t;
        hb[i] = f2bf(t);               // RNE for final bf16 (feeds scores)
      }
      size_t gro = (rowbase + (size_t)row)*32 + n0;
      *(uint2*)&lifto[gro] = make_uint2((unsigned)hb[0] | ((unsigned)hb[1]<<16),
                                        (unsigned)hb[2] | ((unsigned)hb[3]<<16));
      if (net == 0)
        *(float4*)&kout[gro] = make_float4(t4[0], t4[1], t4[2], t4[3]);
    }
  }
}

// ---------------- kernel 2 v4: R14 LDS-transpose scores + bijective XCD-chunk swizzle ---
// R15 change (isolated): logical tile id = (hw_bid & 7)*2048 + (hw_bid >> 3).
// HW round-robins hw_bid across 8 XCDs -> each XCD now owns a CONTIGUOUS logical
// range (8 bh surfaces; co-XCD-resident blocks write adjacent 512B segments of
// the SAME output rows, temporally close through one L2). Targets the remaining
// ~50us of scores' gap to the 168us write floor (cross-XCD write interleave).
// Everything inside the kernel is byte-identical to R14.
__global__ __launch_bounds__(256) void scores_k(
    const unsigned short* __restrict__ qlift,
    const unsigned short* __restrict__ klift,
    float* __restrict__ out)
{
  int orig = blockIdx.x;
  int bid  = (orig & 7) * 2048 + (orig >> 3);   // bijective: 16384 % 8 == 0
  int tc = bid & 15, tr = (bid >> 4) & 15, bh = bid >> 8;
  size_t sbase = (size_t)bh * 2048 * 2048;
  int r0 = tr * 128, c0 = tc * 128;   // r0: t rows (Q), c0: s cols (K)
  int tid = threadIdx.x;

  if (tc > tr){ // fully masked tile: sigmoid(f32_min) == 0
    float4 z = {0.f,0.f,0.f,0.f};
    #pragma unroll
    for (int it=0; it<16; ++it){
      int idx = it*256 + tid;     // 0..4095
      int row = idx >> 5, c4 = idx & 31;
      *(float4*)&out[sbase + (size_t)(r0+row)*2048 + c0 + c4*4] = z;
    }
    return;
  }

  __shared__ float sbuf[4][16][128];   // per-wave 8KB transpose buffer
  int w = tid >> 6, l = tid & 63;
  int lr = l & 15, lg = l >> 4;
  int acol0 = 8*lg;
  float* sw = &sbuf[w][0][0];

  // B operand: Q fragments for t-tiles {w*32, w*32+16}
  const unsigned short* qb = qlift + ((size_t)bh*2048 + r0 + w*32)*32;
  bf16x8 q0 = *(const bf16x8*)(qb + (size_t)lr*32 + acol0);
  bf16x8 q1 = *(const bf16x8*)(qb + (size_t)(16+lr)*32 + acol0);
  bool diag = (tc == tr);

  // A operand: K fragments for the 8 s-tiles (prefetch all, reused both passes)
  const unsigned short* kb = klift + ((size_t)bh*2048 + c0)*32;
  bf16x8 kf[8];
  #pragma unroll
  for (int st8=0; st8<8; ++st8)
    kf[st8] = *(const bf16x8*)(kb + (size_t)(st8*16+lr)*32 + acol0);

  #pragma unroll
  for (int pass=0; pass<2; ++pass){
    bf16x8 qf = pass ? q1 : q0;
    int tbase = r0 + w*32 + pass*16;   // global t of LDS row 0
    int t = tbase + lr;                // this lane's t (for diag predication)

    #pragma unroll
    for (int st8=0; st8<8; ++st8){
      f32x4 z4 = {0.f,0.f,0.f,0.f};
      f32x4 d = MFMA(kf[st8], qf, z4);   // D[row]=s (4lg+i), D[col]=t (lr)
      int scol = c0 + st8*16 + 4*lg;
      f32x4 p;
      #pragma unroll
      for (int i=0;i<4;++i){
        float pv = __builtin_amdgcn_rcpf(1.f + __expf(-d[i]));
        if (diag && (scol + i > t)) pv = 0.f;
        p[i] = pv;
      }
      int fi = (lr*128 + st8*16 + lg*4) ^ ((lr&7)<<2);   // XOR-swizzled float idx
      *(f32x4*)&sw[fi] = p;
    }
    // readback: 8 instructions, each stores TWO 512B contiguous row-bursts
    #pragma unroll
    for (int it=0; it<8; ++it){
      int r  = it*2 + (l>>5);            // LDS row 0..15
      int fi = (r*128 + (l&31)*4) ^ ((r&7)<<2);
      f32x4 v = *(const f32x4*)&sw[fi];
      *(f32x4*)&out[sbase + (size_t)(tbase + r)*2048 + c0 + (l&31)*4] = v;
    }
  }
}

extern "C" void kernel_launch(void* const* d_in, const int* in_sizes, int n_in,
                              void* d_out, int out_size, void* d_ws, size_t ws_size,
                              hipStream_t stream) {
  const float* K   = (const float*)d_in[0];
  const float* Q   = (const float*)d_in[1];
  const float* wk1 = (const float*)d_in[2];  const float* bk1 = (const float*)d_in[3];
  const float* wk2 = (const float*)d_in[4];  const float* bk2 = (const float*)d_in[5];
  const float* wk3 = (const float*)d_in[6];  const float* bk3 = (const float*)d_in[7];
  const float* wq1 = (const float*)d_in[8];  const float* bq1 = (const float*)d_in[9];
  const float* wq2 = (const float*)d_in[10]; const float* bq2 = (const float*)d_in[11];
  const float* wq3 = (const float*)d_in[12]; const float* bq3 = (const float*)d_in[13];
  float* out = (float*)d_out;

  unsigned short* ws    = (unsigned short*)d_ws;
  unsigned short* qlift = ws;                 // 4,194,304 ushorts
  unsigned short* klift = ws + 4194304;       // 4,194,304 ushorts
  unsigned short* wbase = ws + 8388608;       // 2 nets * 2,359,296 ushorts

  hipLaunchKernelGGL(wswz, dim3(256,6), dim3(256), 0, stream,
                     wk1, wk2, wk3, wq1, wq2, wq3, wbase);
  hipLaunchKernelGGL(lift, dim3(4096), dim3(256), 0, stream,
                     K, Q, bk1, bk2, bk3, bq1, bq2, bq3,
                     wbase, qlift, klift, out + 268435456ull);
  hipLaunchKernelGGL(scores_k, dim3(16384), dim3(256), 0, stream,
                     qlift, klift, out);
}